// Round 3
// baseline (409.469 us; speedup 1.0000x reference)
//
#include <hip/hip_runtime.h>
#include <math.h>

// Problem constants
#define BATCH   32768
#define DIMX    64
#define FEATD   128
#define IN1     192      // FEATDIM + DIM
#define WIDTH   1536
#define ONC     896      // DIM * (3K-1)

// Tiling
#define BM      48       // batch rows per block
#define RB      3        // 16-row blocks per block
#define NT      512      // 8 waves
#define H_LD    1544     // h row stride in bf16 elems (1536 + 8 pad)
#define IN_LD   200      // input row stride in bf16 elems (192 + 8 pad)
#define SW_LD   114      // spline scratch row stride in f32 (112 + 2 pad)
#define NBLK    ((BATCH + BM - 1) / BM)   // 683

typedef __attribute__((ext_vector_type(8))) short short8;
typedef __attribute__((ext_vector_type(4))) float f32x4;

#define MFMA_BF16(a,b,c) __builtin_amdgcn_mfma_f32_16x16x32_bf16((a),(b),(c),0,0,0)

__device__ __forceinline__ unsigned short f2bf(float f) {
  unsigned u = __builtin_bit_cast(unsigned, f);
  u += 0x7fffu + ((u >> 16) & 1u);            // round-to-nearest-even
  return (unsigned short)(u >> 16);
}
__device__ __forceinline__ float softplusf(float t) {
  return fmaxf(t, 0.f) + log1pf(expf(-fabsf(t)));
}

// ---------------------------------------------------------------------------
// Pack weight W [N][K] f32 (pre-masked) into MFMA B-fragment tiles, bf16:
//   out[(kb*(N/16)+nb)*512 + lane*8 + j] = bf16( W[nb*16+(lane&15)][kb*32+(lane>>4)*8+j] )
// ---------------------------------------------------------------------------
__global__ __launch_bounds__(256) void pack_w(const float* __restrict__ W,
                                              unsigned short* __restrict__ out,
                                              int N, int K) {
  const int wv = (blockIdx.x * 256 + threadIdx.x) >> 6;   // tile id
  const int lane = threadIdx.x & 63;
  const int ntiles = (K / 32) * (N / 16);
  if (wv >= ntiles) return;
  const int nbt = N / 16;
  const int kb = wv / nbt, nb = wv - kb * nbt;
  const int n = nb * 16 + (lane & 15);
  const int k = kb * 32 + (lane >> 4) * 8;
  const float* src = W + (size_t)n * K + k;
  const float4 v0 = *(const float4*)src;
  const float4 v1 = *(const float4*)(src + 4);
  short8 o;
  o[0] = (short)f2bf(v0.x); o[1] = (short)f2bf(v0.y);
  o[2] = (short)f2bf(v0.z); o[3] = (short)f2bf(v0.w);
  o[4] = (short)f2bf(v1.x); o[5] = (short)f2bf(v1.y);
  o[6] = (short)f2bf(v1.z); o[7] = (short)f2bf(v1.w);
  *(short8*)(out + ((size_t)wv * 64 + lane) * 8) = o;
}

__device__ __forceinline__ short8 lda_frag(const unsigned short* h, int ld,
                                           int rb, int kb, int l15, int l4) {
  return *(const short8*)(h + (size_t)(rb * 16 + l15) * ld + kb * 32 + l4 * 8);
}
__device__ __forceinline__ short8 ldb_frag(const unsigned short* p, int tile, int lane) {
  return *(const short8*)(p + ((size_t)tile * 64 + lane) * 8);
}

// ---------------------------------------------------------------------------
// bias + leaky + LayerNorm on MFMA C fragments (12 n-tiles/wave, RB row-blocks)
// result written as bf16 into hbuf (row-major, stride H_LD).
// ---------------------------------------------------------------------------
__device__ __forceinline__ void act_ln(f32x4 acc[RB][12],
    const float* __restrict__ bias, const float* __restrict__ gam,
    const float* __restrict__ bet, int colbase,
    unsigned short* hbuf, float* red, float* mstd,
    int t, int w, int l15, int l4)
{
  #pragma unroll
  for (int nb = 0; nb < 12; ++nb) {
    const float bb = bias[colbase + nb * 16 + l15];
    #pragma unroll
    for (int rb = 0; rb < RB; ++rb)
      #pragma unroll
      for (int i = 0; i < 4; ++i) {
        float v = acc[rb][nb][i] + bb;
        acc[rb][nb][i] = v > 0.f ? v : 0.2f * v;
      }
  }
  #pragma unroll
  for (int rb = 0; rb < RB; ++rb)
    #pragma unroll
    for (int i = 0; i < 4; ++i) {
      float ss = 0.f, qq = 0.f;
      #pragma unroll
      for (int nb = 0; nb < 12; ++nb) {
        const float v = acc[rb][nb][i];
        ss += v; qq += v * v;
      }
      #pragma unroll
      for (int o = 1; o < 16; o <<= 1) { ss += __shfl_xor(ss, o, 64); qq += __shfl_xor(qq, o, 64); }
      if (l15 == 0) {
        const int r = rb * 16 + l4 * 4 + i;
        red[w * 96 + r] = ss;
        red[w * 96 + 48 + r] = qq;
      }
    }
  __syncthreads();
  if (t < BM) {
    float ss = 0.f, qq = 0.f;
    #pragma unroll
    for (int w8 = 0; w8 < 8; ++w8) { ss += red[w8 * 96 + t]; qq += red[w8 * 96 + 48 + t]; }
    const float m = ss * (1.f / (float)WIDTH);
    const float v = qq * (1.f / (float)WIDTH) - m * m;
    mstd[t] = m;
    mstd[48 + t] = rsqrtf(fmaxf(v, 0.f) + 1e-5f);
  }
  __syncthreads();
  float mm[RB][4], rr[RB][4];
  #pragma unroll
  for (int rb = 0; rb < RB; ++rb)
    #pragma unroll
    for (int i = 0; i < 4; ++i) {
      const int r = rb * 16 + l4 * 4 + i;
      mm[rb][i] = mstd[r]; rr[rb][i] = mstd[48 + r];
    }
  #pragma unroll
  for (int nb = 0; nb < 12; ++nb) {
    const int col = colbase + nb * 16 + l15;
    const float gg = gam[col], ee = bet[col];
    #pragma unroll
    for (int rb = 0; rb < RB; ++rb)
      #pragma unroll
      for (int i = 0; i < 4; ++i) {
        const int r = rb * 16 + l4 * 4 + i;
        hbuf[(size_t)r * H_LD + col] = f2bf((acc[rb][nb][i] - mm[rb][i]) * rr[rb][i] * gg + ee);
      }
  }
  __syncthreads();
}

// ---------------------------------------------------------------------------
// RQS spline for one (row, dim): o = 14 params [W0..4, H0..4, D0..3]
// ---------------------------------------------------------------------------
__device__ __forceinline__ void spline_eval(const float* __restrict__ o, float xv,
                                            float& zret, float& ladd) {
  const float Wv0 = o[0], Wv1 = o[1], Wv2 = o[2], Wv3 = o[3], Wv4 = o[4];
  const float Hv0 = o[5], Hv1 = o[6], Hv2 = o[7], Hv3 = o[8], Hv4 = o[9];
  const float Dv0 = o[10], Dv1 = o[11], Dv2 = o[12], Dv3 = o[13];

  float mw = fmaxf(fmaxf(fmaxf(Wv0, Wv1), fmaxf(Wv2, Wv3)), Wv4);
  float e0 = expf(Wv0 - mw), e1 = expf(Wv1 - mw), e2 = expf(Wv2 - mw),
        e3 = expf(Wv3 - mw), e4 = expf(Wv4 - mw);
  float inv = 0.995f / (e0 + e1 + e2 + e3 + e4);
  const float wd0 = 0.001f + e0 * inv, wd1 = 0.001f + e1 * inv,
              wd2 = 0.001f + e2 * inv, wd3 = 0.001f + e3 * inv;
  const float c1 = wd0, c2 = c1 + wd1, c3 = c2 + wd2, c4 = c3 + wd3;
  const float wi0 = c1, wi1 = c2 - c1, wi2 = c3 - c2, wi3 = c4 - c3, wi4 = 1.f - c4;

  float mh = fmaxf(fmaxf(fmaxf(Hv0, Hv1), fmaxf(Hv2, Hv3)), Hv4);
  float f0 = expf(Hv0 - mh), f1e = expf(Hv1 - mh), f2e = expf(Hv2 - mh),
        f3e = expf(Hv3 - mh), f4e = expf(Hv4 - mh);
  float invh = 0.995f / (f0 + f1e + f2e + f3e + f4e);
  const float hd0 = 0.001f + f0 * invh, hd1 = 0.001f + f1e * invh,
              hd2 = 0.001f + f2e * invh, hd3 = 0.001f + f3e * invh;
  const float g1c = hd0, g2c = g1c + hd1, g3c = g2c + hd2, g4c = g3c + hd3;
  const float hi0 = g1c, hi1 = g2c - g1c, hi2 = g3c - g2c, hi3 = g4c - g3c, hi4 = 1.f - g4c;

  const float dv1 = 0.001f + softplusf(Dv0), dv2 = 0.001f + softplusf(Dv1),
              dv3 = 0.001f + softplusf(Dv2), dv4 = 0.001f + softplusf(Dv3);

  const float s = 1.f / (1.f + expf(-xv));
  const int idx = (int)(s >= c1) + (int)(s >= c2) + (int)(s >= c3) + (int)(s >= c4);

  const float in_cw = idx == 0 ? 0.f : idx == 1 ? c1  : idx == 2 ? c2  : idx == 3 ? c3  : c4;
  const float in_w  = idx == 0 ? wi0 : idx == 1 ? wi1 : idx == 2 ? wi2 : idx == 3 ? wi3 : wi4;
  const float in_h  = idx == 0 ? hi0 : idx == 1 ? hi1 : idx == 2 ? hi2 : idx == 3 ? hi3 : hi4;
  const float in_ch = idx == 0 ? 0.f : idx == 1 ? g1c : idx == 2 ? g2c : idx == 3 ? g3c : g4c;
  const float d0    = idx == 0 ? 1.f : idx == 1 ? dv1 : idx == 2 ? dv2 : idx == 3 ? dv3 : dv4;
  const float d1    = idx == 0 ? dv1 : idx == 1 ? dv2 : idx == 2 ? dv3 : idx == 3 ? dv4 : 1.f;

  const float delta = in_h / in_w;
  const float th  = (s - in_cw) / in_w;
  const float omt = 1.f - th;
  const float t1  = th * omt;
  const float num = in_h * (delta * th * th + d0 * t1);
  const float den = delta + (d0 + d1 - 2.f * delta) * t1;
  float outv = in_ch + num / den;
  const float dnum = delta * delta * (d1 * th * th + 2.f * delta * t1 + d0 * omt * omt);
  const float lad_rqs = logf(dnum) - 2.f * logf(den);
  outv = outv * 0.999998f + 1e-6f;
  const float lo = logf(outv), l1m = logf(1.f - outv);
  const float logds = -softplusf(-xv) - softplusf(xv);
  zret = lo - l1m;
  ladd = logds + lad_rqs - lo - l1m;
}

// ---------------------------------------------------------------------------
// Fused kernel
// ---------------------------------------------------------------------------
__global__ __launch_bounds__(NT, 2) void nsf_fused(
    const float* __restrict__ x, const float* __restrict__ feat,
    const unsigned short* __restrict__ w1p, const float* __restrict__ b1,
    const float* __restrict__ g1, const float* __restrict__ be1,
    const unsigned short* __restrict__ w2p, const float* __restrict__ b2,
    const float* __restrict__ g2, const float* __restrict__ be2,
    const unsigned short* __restrict__ w3p, const float* __restrict__ b3,
    float* __restrict__ zout, float* __restrict__ ladout)
{
  // hbuf: 48*1544*2 = 148224 B; red: 768 f32; mstd: 96 f32  -> 151680 B total
  __shared__ __align__(16) unsigned char smem[BM * H_LD * 2 + 768 * 4 + 96 * 4];
  unsigned short* hbuf = (unsigned short*)smem;
  float* red  = (float*)(smem + BM * H_LD * 2);
  float* mstd = red + 768;

  const int t = threadIdx.x;
  const int lane = t & 63, w = t >> 6;
  const int l15 = lane & 15, l4 = lane >> 4;
  const int b0 = blockIdx.x * BM;

  // ---- stage concat([feat, x]) as bf16, rows clamped for the tail block ----
  for (int idx = t; idx < BM * IN1; idx += NT) {
    const int r = idx / IN1, c = idx - r * IN1;
    int row = b0 + r; if (row >= BATCH) row = BATCH - 1;
    const float v = (c < FEATD) ? feat[(size_t)row * FEATD + c]
                                : x[(size_t)row * DIMX + (c - FEATD)];
    hbuf[r * IN_LD + c] = f2bf(v);
  }
  __syncthreads();

  // ================= GEMM1: K=192 (6 kblks), cols w*192..+192 ================
  f32x4 acc[RB][12];
  #pragma unroll
  for (int rb = 0; rb < RB; ++rb)
    #pragma unroll
    for (int nb = 0; nb < 12; ++nb) acc[rb][nb] = (f32x4){0.f, 0.f, 0.f, 0.f};

  #pragma unroll 1
  for (int kb = 0; kb < 6; ++kb) {
    short8 bv[12];
    #pragma unroll
    for (int nb = 0; nb < 12; ++nb) bv[nb] = ldb_frag(w1p, kb * 96 + w * 12 + nb, lane);
    short8 af[RB];
    #pragma unroll
    for (int rb = 0; rb < RB; ++rb) af[rb] = lda_frag(hbuf, IN_LD, rb, kb, l15, l4);
    #pragma unroll
    for (int nb = 0; nb < 12; ++nb)
      #pragma unroll
      for (int rb = 0; rb < RB; ++rb)
        acc[rb][nb] = MFMA_BF16(af[rb], bv[nb], acc[rb][nb]);
  }
  act_ln(acc, b1, g1, be1, w * 192, hbuf, red, mstd, t, w, l15, l4);

  // ================= GEMM2: K=1536 (48 kblks), two 6-tile passes =============
  #pragma unroll
  for (int rb = 0; rb < RB; ++rb)
    #pragma unroll
    for (int nb = 0; nb < 12; ++nb) acc[rb][nb] = (f32x4){0.f, 0.f, 0.f, 0.f};

  #pragma unroll
  for (int g = 0; g < 2; ++g) {
    short8 bA[6], bB[6];
    #pragma unroll
    for (int nb = 0; nb < 6; ++nb) bA[nb] = ldb_frag(w2p, w * 12 + g * 6 + nb, lane);
    #pragma unroll 1
    for (int kb = 0; kb < 48; kb += 2) {
      #pragma unroll
      for (int nb = 0; nb < 6; ++nb) bB[nb] = ldb_frag(w2p, (kb + 1) * 96 + w * 12 + g * 6 + nb, lane);
      {
        short8 af[RB];
        #pragma unroll
        for (int rb = 0; rb < RB; ++rb) af[rb] = lda_frag(hbuf, H_LD, rb, kb, l15, l4);
        #pragma unroll
        for (int nb = 0; nb < 6; ++nb)
          #pragma unroll
          for (int rb = 0; rb < RB; ++rb)
            acc[rb][g * 6 + nb] = MFMA_BF16(af[rb], bA[nb], acc[rb][g * 6 + nb]);
      }
      if (kb + 2 < 48) {
        #pragma unroll
        for (int nb = 0; nb < 6; ++nb) bA[nb] = ldb_frag(w2p, (kb + 2) * 96 + w * 12 + g * 6 + nb, lane);
      }
      {
        short8 af[RB];
        #pragma unroll
        for (int rb = 0; rb < RB; ++rb) af[rb] = lda_frag(hbuf, H_LD, rb, kb + 1, l15, l4);
        #pragma unroll
        for (int nb = 0; nb < 6; ++nb)
          #pragma unroll
          for (int rb = 0; rb < RB; ++rb)
            acc[rb][g * 6 + nb] = MFMA_BF16(af[rb], bB[nb], acc[rb][g * 6 + nb]);
      }
    }
  }
  act_ln(acc, b2, g2, be2, w * 192, hbuf, red, mstd, t, w, l15, l4);

  // ================= GEMM3: N=896, wave cols w*112..+112 (7 tiles) ===========
  f32x4 acc3[RB][7];
  #pragma unroll
  for (int rb = 0; rb < RB; ++rb)
    #pragma unroll
    for (int nb = 0; nb < 7; ++nb) acc3[rb][nb] = (f32x4){0.f, 0.f, 0.f, 0.f};

  {
    short8 bA[7], bB[7];
    #pragma unroll
    for (int nb = 0; nb < 7; ++nb) bA[nb] = ldb_frag(w3p, w * 7 + nb, lane);
    #pragma unroll 1
    for (int kb = 0; kb < 48; kb += 2) {
      #pragma unroll
      for (int nb = 0; nb < 7; ++nb) bB[nb] = ldb_frag(w3p, (kb + 1) * 56 + w * 7 + nb, lane);
      {
        short8 af[RB];
        #pragma unroll
        for (int rb = 0; rb < RB; ++rb) af[rb] = lda_frag(hbuf, H_LD, rb, kb, l15, l4);
        #pragma unroll
        for (int nb = 0; nb < 7; ++nb)
          #pragma unroll
          for (int rb = 0; rb < RB; ++rb)
            acc3[rb][nb] = MFMA_BF16(af[rb], bA[nb], acc3[rb][nb]);
      }
      if (kb + 2 < 48) {
        #pragma unroll
        for (int nb = 0; nb < 7; ++nb) bA[nb] = ldb_frag(w3p, (kb + 2) * 56 + w * 7 + nb, lane);
      }
      {
        short8 af[RB];
        #pragma unroll
        for (int rb = 0; rb < RB; ++rb) af[rb] = lda_frag(hbuf, H_LD, rb, kb + 1, l15, l4);
        #pragma unroll
        for (int nb = 0; nb < 7; ++nb)
          #pragma unroll
          for (int rb = 0; rb < RB; ++rb)
            acc3[rb][nb] = MFMA_BF16(af[rb], bB[nb], acc3[rb][nb]);
      }
    }
  }
  __syncthreads();   // all hbuf A-reads done; scratch may now alias hbuf

  // ================= spline: wave w owns dims 8w..8w+7, all rows =============
  // per-wave f32 scratch [16][SW_LD] aliased into hbuf region
  float* sw = (float*)smem + (size_t)w * (16 * SW_LD);

  #pragma unroll 1
  for (int rb = 0; rb < RB; ++rb) {
    // write this 16-row chunk of GEMM3 output (+bias) into scratch
    #pragma unroll
    for (int nb = 0; nb < 7; ++nb) {
      const int col = nb * 16 + l15;
      const float bb = b3[w * 112 + col];
      #pragma unroll
      for (int i = 0; i < 4; ++i)
        sw[(l4 * 4 + i) * SW_LD + col] = acc3[rb][nb][i] + bb;
    }
    __syncthreads();
    // lane -> (row' = l15, dims d' = l4 and l4+4)
    const int grow = b0 + rb * 16 + l15;
    const bool valid = grow < BATCH;
    const int gr = valid ? grow : BATCH - 1;
    const int d1i = l4, d2i = l4 + 4;
    float z1, lad1, z2, lad2;
    const float xv1 = x[(size_t)gr * DIMX + w * 8 + d1i];
    const float xv2 = x[(size_t)gr * DIMX + w * 8 + d2i];
    spline_eval(&sw[l15 * SW_LD + d1i * 14], xv1, z1, lad1);
    spline_eval(&sw[l15 * SW_LD + d2i * 14], xv2, z2, lad2);
    if (valid) {
      zout[(size_t)grow * DIMX + w * 8 + d1i] = z1;
      zout[(size_t)grow * DIMX + w * 8 + d2i] = z2;
    }
    float ls = lad1 + lad2;
    ls += __shfl_xor(ls, 16, 64);
    ls += __shfl_xor(ls, 32, 64);
    if (lane < 16) red[w * 48 + rb * 16 + l15] = ls;   // wave's 8-dim row partial
    __syncthreads();
  }

  if (t < BM && b0 + t < BATCH) {
    float s = 0.f;
    #pragma unroll
    for (int w8 = 0; w8 < 8; ++w8) s += red[w8 * 48 + t];
    ladout[b0 + t] = s;
  }
}

// ---------------------------------------------------------------------------
extern "C" void kernel_launch(void* const* d_in, const int* in_sizes, int n_in,
                              void* d_out, int out_size, void* d_ws, size_t ws_size,
                              hipStream_t stream) {
  const float* x   = (const float*)d_in[0];
  const float* feat= (const float*)d_in[1];
  const float* w1  = (const float*)d_in[2];   // [1536][192]  pre-masked
  const float* b1  = (const float*)d_in[3];
  const float* g1  = (const float*)d_in[4];
  const float* be1 = (const float*)d_in[5];
  const float* w2  = (const float*)d_in[6];   // [1536][1536] pre-masked
  const float* b2  = (const float*)d_in[7];
  const float* g2  = (const float*)d_in[8];
  const float* be2 = (const float*)d_in[9];
  const float* w3  = (const float*)d_in[10];  // [896][1536]  pre-masked
  const float* b3  = (const float*)d_in[11];
  // masks unused: weights arrive pre-masked (mask is 0/1, idempotent).

  unsigned short* w1p = (unsigned short*)d_ws;                 // 576 tiles
  unsigned short* w2p = w1p + (size_t)576 * 512;               // 4608 tiles
  unsigned short* w3p = w2p + (size_t)4608 * 512;              // 2688 tiles

  pack_w<<<144,  256, 0, stream>>>(w1, w1p, WIDTH, IN1);
  pack_w<<<1152, 256, 0, stream>>>(w2, w2p, WIDTH, WIDTH);
  pack_w<<<672,  256, 0, stream>>>(w3, w3p, ONC, WIDTH);

  float* zout   = (float*)d_out;
  float* ladout = zout + (size_t)BATCH * DIMX;
  nsf_fused<<<NBLK, NT, 0, stream>>>(x, feat, w1p, b1, g1, be1,
                                     w2p, b2, g2, be2, w3p, b3,
                                     zout, ladout);
}

// Round 4
// 396.606 us; speedup vs baseline: 1.0324x; 1.0324x over previous
//
#include <hip/hip_runtime.h>
#include <math.h>

// Problem constants
#define BATCH   32768
#define DIMX    64
#define FEATD   128
#define IN1     192      // FEATDIM + DIM
#define WIDTH   1536
#define ONC     896      // DIM * (3K-1)

// Tiling
#define BM      48       // batch rows per block
#define RB      3        // 16-row blocks per block
#define NT      512      // 8 waves
#define H_LD    1544     // h row stride in bf16 elems (1536 + 8 pad)
#define IN_LD   200      // input row stride in bf16 elems (192 + 8 pad)
#define SW_LD   114      // spline scratch row stride in f32 (112 + 2 pad)
#define NBLK    ((BATCH + BM - 1) / BM)   // 683

typedef __attribute__((ext_vector_type(8))) short short8;
typedef __attribute__((ext_vector_type(4))) float f32x4;

#define MFMA_BF16(a,b,c) __builtin_amdgcn_mfma_f32_16x16x32_bf16((a),(b),(c),0,0,0)

__device__ __forceinline__ unsigned short f2bf(float f) {
  unsigned u = __builtin_bit_cast(unsigned, f);
  u += 0x7fffu + ((u >> 16) & 1u);            // round-to-nearest-even
  return (unsigned short)(u >> 16);
}
__device__ __forceinline__ float softplusf(float t) {
  return fmaxf(t, 0.f) + log1pf(expf(-fabsf(t)));
}

// ---------------------------------------------------------------------------
// Pack weight W [N][K] f32 (pre-masked) into MFMA B-fragment tiles, bf16:
//   out[(kb*(N/16)+nb)*512 + lane*8 + j] = bf16( W[nb*16+(lane&15)][kb*32+(lane>>4)*8+j] )
// ---------------------------------------------------------------------------
__global__ __launch_bounds__(256) void pack_w(const float* __restrict__ W,
                                              unsigned short* __restrict__ out,
                                              int N, int K) {
  const int wv = (blockIdx.x * 256 + threadIdx.x) >> 6;   // tile id
  const int lane = threadIdx.x & 63;
  const int ntiles = (K / 32) * (N / 16);
  if (wv >= ntiles) return;
  const int nbt = N / 16;
  const int kb = wv / nbt, nb = wv - kb * nbt;
  const int n = nb * 16 + (lane & 15);
  const int k = kb * 32 + (lane >> 4) * 8;
  const float* src = W + (size_t)n * K + k;
  const float4 v0 = *(const float4*)src;
  const float4 v1 = *(const float4*)(src + 4);
  short8 o;
  o[0] = (short)f2bf(v0.x); o[1] = (short)f2bf(v0.y);
  o[2] = (short)f2bf(v0.z); o[3] = (short)f2bf(v0.w);
  o[4] = (short)f2bf(v1.x); o[5] = (short)f2bf(v1.y);
  o[6] = (short)f2bf(v1.z); o[7] = (short)f2bf(v1.w);
  *(short8*)(out + ((size_t)wv * 64 + lane) * 8) = o;
}

// ---------------------------------------------------------------------------
// bias + leaky + LayerNorm on MFMA C fragments (12 n-tiles/wave, RB row-blocks)
// result written as bf16 into hbuf (row-major, stride H_LD).
// ---------------------------------------------------------------------------
__device__ __forceinline__ void act_ln(f32x4 acc[RB][12],
    const float* __restrict__ bias, const float* __restrict__ gam,
    const float* __restrict__ bet, int colbase,
    unsigned short* hbuf, float* red, float* mstd,
    int t, int w, int l15, int l4)
{
  #pragma unroll
  for (int nb = 0; nb < 12; ++nb) {
    const float bb = bias[colbase + nb * 16 + l15];
    #pragma unroll
    for (int rb = 0; rb < RB; ++rb)
      #pragma unroll
      for (int i = 0; i < 4; ++i) {
        float v = acc[rb][nb][i] + bb;
        acc[rb][nb][i] = v > 0.f ? v : 0.2f * v;
      }
  }
  #pragma unroll
  for (int rb = 0; rb < RB; ++rb)
    #pragma unroll
    for (int i = 0; i < 4; ++i) {
      float ss = 0.f, qq = 0.f;
      #pragma unroll
      for (int nb = 0; nb < 12; ++nb) {
        const float v = acc[rb][nb][i];
        ss += v; qq += v * v;
      }
      #pragma unroll
      for (int o = 1; o < 16; o <<= 1) { ss += __shfl_xor(ss, o, 64); qq += __shfl_xor(qq, o, 64); }
      if (l15 == 0) {
        const int r = rb * 16 + l4 * 4 + i;
        red[w * 96 + r] = ss;
        red[w * 96 + 48 + r] = qq;
      }
    }
  __syncthreads();
  if (t < BM) {
    float ss = 0.f, qq = 0.f;
    #pragma unroll
    for (int w8 = 0; w8 < 8; ++w8) { ss += red[w8 * 96 + t]; qq += red[w8 * 96 + 48 + t]; }
    const float m = ss * (1.f / (float)WIDTH);
    const float v = qq * (1.f / (float)WIDTH) - m * m;
    mstd[t] = m;
    mstd[48 + t] = rsqrtf(fmaxf(v, 0.f) + 1e-5f);
  }
  __syncthreads();
  float mm[RB][4], rr[RB][4];
  #pragma unroll
  for (int rb = 0; rb < RB; ++rb)
    #pragma unroll
    for (int i = 0; i < 4; ++i) {
      const int r = rb * 16 + l4 * 4 + i;
      mm[rb][i] = mstd[r]; rr[rb][i] = mstd[48 + r];
    }
  // writes: per-rb base pointer, everything else immediate ds offsets
  #pragma unroll
  for (int rb = 0; rb < RB; ++rb) {
    unsigned short* wp = hbuf + (size_t)(rb * 16 + l4 * 4) * H_LD + colbase + l15;
    #pragma unroll
    for (int nb = 0; nb < 12; ++nb) {
      const int col = colbase + nb * 16 + l15;
      const float gg = gam[col], ee = bet[col];
      #pragma unroll
      for (int i = 0; i < 4; ++i)
        wp[(size_t)i * H_LD + nb * 16] =
            f2bf((acc[rb][nb][i] - mm[rb][i]) * rr[rb][i] * gg + ee);
    }
  }
  __syncthreads();
}

// ---------------------------------------------------------------------------
// RQS spline for one (row, dim): o = 14 params [W0..4, H0..4, D0..3]
// ---------------------------------------------------------------------------
__device__ __forceinline__ void spline_eval(const float* __restrict__ o, float xv,
                                            float& zret, float& ladd) {
  const float Wv0 = o[0], Wv1 = o[1], Wv2 = o[2], Wv3 = o[3], Wv4 = o[4];
  const float Hv0 = o[5], Hv1 = o[6], Hv2 = o[7], Hv3 = o[8], Hv4 = o[9];
  const float Dv0 = o[10], Dv1 = o[11], Dv2 = o[12], Dv3 = o[13];

  float mw = fmaxf(fmaxf(fmaxf(Wv0, Wv1), fmaxf(Wv2, Wv3)), Wv4);
  float e0 = expf(Wv0 - mw), e1 = expf(Wv1 - mw), e2 = expf(Wv2 - mw),
        e3 = expf(Wv3 - mw), e4 = expf(Wv4 - mw);
  float inv = 0.995f / (e0 + e1 + e2 + e3 + e4);
  const float wd0 = 0.001f + e0 * inv, wd1 = 0.001f + e1 * inv,
              wd2 = 0.001f + e2 * inv, wd3 = 0.001f + e3 * inv;
  const float c1 = wd0, c2 = c1 + wd1, c3 = c2 + wd2, c4 = c3 + wd3;
  const float wi0 = c1, wi1 = c2 - c1, wi2 = c3 - c2, wi3 = c4 - c3, wi4 = 1.f - c4;

  float mh = fmaxf(fmaxf(fmaxf(Hv0, Hv1), fmaxf(Hv2, Hv3)), Hv4);
  float f0 = expf(Hv0 - mh), f1e = expf(Hv1 - mh), f2e = expf(Hv2 - mh),
        f3e = expf(Hv3 - mh), f4e = expf(Hv4 - mh);
  float invh = 0.995f / (f0 + f1e + f2e + f3e + f4e);
  const float hd0 = 0.001f + f0 * invh, hd1 = 0.001f + f1e * invh,
              hd2 = 0.001f + f2e * invh, hd3 = 0.001f + f3e * invh;
  const float g1c = hd0, g2c = g1c + hd1, g3c = g2c + hd2, g4c = g3c + hd3;
  const float hi0 = g1c, hi1 = g2c - g1c, hi2 = g3c - g2c, hi3 = g4c - g3c, hi4 = 1.f - g4c;

  const float dv1 = 0.001f + softplusf(Dv0), dv2 = 0.001f + softplusf(Dv1),
              dv3 = 0.001f + softplusf(Dv2), dv4 = 0.001f + softplusf(Dv3);

  const float s = 1.f / (1.f + expf(-xv));
  const int idx = (int)(s >= c1) + (int)(s >= c2) + (int)(s >= c3) + (int)(s >= c4);

  const float in_cw = idx == 0 ? 0.f : idx == 1 ? c1  : idx == 2 ? c2  : idx == 3 ? c3  : c4;
  const float in_w  = idx == 0 ? wi0 : idx == 1 ? wi1 : idx == 2 ? wi2 : idx == 3 ? wi3 : wi4;
  const float in_h  = idx == 0 ? hi0 : idx == 1 ? hi1 : idx == 2 ? hi2 : idx == 3 ? hi3 : hi4;
  const float in_ch = idx == 0 ? 0.f : idx == 1 ? g1c : idx == 2 ? g2c : idx == 3 ? g3c : g4c;
  const float d0    = idx == 0 ? 1.f : idx == 1 ? dv1 : idx == 2 ? dv2 : idx == 3 ? dv3 : dv4;
  const float d1    = idx == 0 ? dv1 : idx == 1 ? dv2 : idx == 2 ? dv3 : idx == 3 ? dv4 : 1.f;

  const float delta = in_h / in_w;
  const float th  = (s - in_cw) / in_w;
  const float omt = 1.f - th;
  const float t1  = th * omt;
  const float num = in_h * (delta * th * th + d0 * t1);
  const float den = delta + (d0 + d1 - 2.f * delta) * t1;
  float outv = in_ch + num / den;
  const float dnum = delta * delta * (d1 * th * th + 2.f * delta * t1 + d0 * omt * omt);
  const float lad_rqs = logf(dnum) - 2.f * logf(den);
  outv = outv * 0.999998f + 1e-6f;
  const float lo = logf(outv), l1m = logf(1.f - outv);
  const float logds = -softplusf(-xv) - softplusf(xv);
  zret = lo - l1m;
  ladd = logds + lad_rqs - lo - l1m;
}

// ---------------------------------------------------------------------------
// Fused kernel
// ---------------------------------------------------------------------------
__global__ __launch_bounds__(NT, 2) void nsf_fused(
    const float* __restrict__ x, const float* __restrict__ feat,
    const unsigned short* __restrict__ w1p, const float* __restrict__ b1,
    const float* __restrict__ g1, const float* __restrict__ be1,
    const unsigned short* __restrict__ w2p, const float* __restrict__ b2,
    const float* __restrict__ g2, const float* __restrict__ be2,
    const unsigned short* __restrict__ w3p, const float* __restrict__ b3,
    float* __restrict__ zout, float* __restrict__ ladout)
{
  // hbuf: 48*1544*2 = 148224 B; red: 768 f32; mstd: 96 f32  -> 151680 B total
  __shared__ __align__(16) unsigned char smem[BM * H_LD * 2 + 768 * 4 + 96 * 4];
  unsigned short* hbuf = (unsigned short*)smem;
  float* red  = (float*)(smem + BM * H_LD * 2);
  float* mstd = red + 768;

  const int t = threadIdx.x;
  const int lane = t & 63, w = t >> 6;
  const int l15 = lane & 15, l4 = lane >> 4;
  const int b0 = blockIdx.x * BM;

  // ---- stage concat([feat, x]) as bf16, rows clamped for the tail block ----
  for (int idx = t; idx < BM * IN1; idx += NT) {
    const int r = idx / IN1, c = idx - r * IN1;
    int row = b0 + r; if (row >= BATCH) row = BATCH - 1;
    const float v = (c < FEATD) ? feat[(size_t)row * FEATD + c]
                                : x[(size_t)row * DIMX + (c - FEATD)];
    hbuf[r * IN_LD + c] = f2bf(v);
  }
  __syncthreads();

  // per-lane fragment base offsets
  const int aoff = l15 * 1 /*row*/ , koff = l4 * 8;

  // ================= GEMM1: K=192 (6 kblks), cols w*192..+192 ================
  f32x4 acc[RB][12];
  #pragma unroll
  for (int rb = 0; rb < RB; ++rb)
    #pragma unroll
    for (int nb = 0; nb < 12; ++nb) acc[rb][nb] = (f32x4){0.f, 0.f, 0.f, 0.f};

  {
    // A base pointers (ds offsets fold kb*64B immediates)
    const unsigned short* pA0 = hbuf + (size_t)(0 * 16 + l15) * IN_LD + koff;
    const unsigned short* pA1 = hbuf + (size_t)(1 * 16 + l15) * IN_LD + koff;
    const unsigned short* pA2 = hbuf + (size_t)(2 * 16 + l15) * IN_LD + koff;
    const unsigned short* pB = w1p + (((size_t)(w * 12)) * 64 + lane) * 8;
    const size_t kstr = (size_t)96 * 512;   // elems per kb step
    #pragma unroll 1
    for (int kb = 0; kb < 6; ++kb) {
      short8 bv[12];
      #pragma unroll
      for (int nb = 0; nb < 12; ++nb) bv[nb] = *(const short8*)(pB + nb * 512);
      pB += kstr;
      short8 a0 = *(const short8*)(pA0 + kb * 32);
      short8 a1 = *(const short8*)(pA1 + kb * 32);
      short8 a2 = *(const short8*)(pA2 + kb * 32);
      __builtin_amdgcn_s_setprio(1);
      #pragma unroll
      for (int nb = 0; nb < 12; ++nb) {
        acc[0][nb] = MFMA_BF16(a0, bv[nb], acc[0][nb]);
        acc[1][nb] = MFMA_BF16(a1, bv[nb], acc[1][nb]);
        acc[2][nb] = MFMA_BF16(a2, bv[nb], acc[2][nb]);
      }
      __builtin_amdgcn_s_setprio(0);
    }
  }
  act_ln(acc, b1, g1, be1, w * 192, hbuf, red, mstd, t, w, l15, l4);

  // ================= GEMM2: K=1536 (48 kblks), two 6-tile passes =============
  #pragma unroll
  for (int rb = 0; rb < RB; ++rb)
    #pragma unroll
    for (int nb = 0; nb < 12; ++nb) acc[rb][nb] = (f32x4){0.f, 0.f, 0.f, 0.f};

  {
    const unsigned short* pA0 = hbuf + (size_t)(0 * 16 + l15) * H_LD + koff;
    const unsigned short* pA1 = hbuf + (size_t)(1 * 16 + l15) * H_LD + koff;
    const unsigned short* pA2 = hbuf + (size_t)(2 * 16 + l15) * H_LD + koff;
    const size_t kstr = (size_t)96 * 512;

    #pragma unroll
    for (int g = 0; g < 2; ++g) {
      const unsigned short* pB = w2p + (((size_t)(w * 12 + g * 6)) * 64 + lane) * 8;
      short8 bA[6], bB[6];
      #pragma unroll
      for (int nb = 0; nb < 6; ++nb) bA[nb] = *(const short8*)(pB + nb * 512);
      pB += kstr;
      #pragma unroll 1
      for (int kb = 0; kb < 48; kb += 2) {
        #pragma unroll
        for (int nb = 0; nb < 6; ++nb) bB[nb] = *(const short8*)(pB + nb * 512);
        pB += kstr;
        {
          short8 a0 = *(const short8*)(pA0 + kb * 32);
          short8 a1 = *(const short8*)(pA1 + kb * 32);
          short8 a2 = *(const short8*)(pA2 + kb * 32);
          __builtin_amdgcn_s_setprio(1);
          #pragma unroll
          for (int nb = 0; nb < 6; ++nb) {
            acc[0][g * 6 + nb] = MFMA_BF16(a0, bA[nb], acc[0][g * 6 + nb]);
            acc[1][g * 6 + nb] = MFMA_BF16(a1, bA[nb], acc[1][g * 6 + nb]);
            acc[2][g * 6 + nb] = MFMA_BF16(a2, bA[nb], acc[2][g * 6 + nb]);
          }
          __builtin_amdgcn_s_setprio(0);
        }
        if (kb + 2 < 48) {
          #pragma unroll
          for (int nb = 0; nb < 6; ++nb) bA[nb] = *(const short8*)(pB + nb * 512);
        }
        pB += kstr;
        {
          short8 a0 = *(const short8*)(pA0 + kb * 32 + 32);
          short8 a1 = *(const short8*)(pA1 + kb * 32 + 32);
          short8 a2 = *(const short8*)(pA2 + kb * 32 + 32);
          __builtin_amdgcn_s_setprio(1);
          #pragma unroll
          for (int nb = 0; nb < 6; ++nb) {
            acc[0][g * 6 + nb] = MFMA_BF16(a0, bB[nb], acc[0][g * 6 + nb]);
            acc[1][g * 6 + nb] = MFMA_BF16(a1, bB[nb], acc[1][g * 6 + nb]);
            acc[2][g * 6 + nb] = MFMA_BF16(a2, bB[nb], acc[2][g * 6 + nb]);
          }
          __builtin_amdgcn_s_setprio(0);
        }
      }
    }
  }
  act_ln(acc, b2, g2, be2, w * 192, hbuf, red, mstd, t, w, l15, l4);

  // ================= GEMM3: N=896, wave cols w*112..+112 (7 tiles) ===========
  f32x4 acc3[RB][7];
  #pragma unroll
  for (int rb = 0; rb < RB; ++rb)
    #pragma unroll
    for (int nb = 0; nb < 7; ++nb) acc3[rb][nb] = (f32x4){0.f, 0.f, 0.f, 0.f};

  {
    const unsigned short* pA0 = hbuf + (size_t)(0 * 16 + l15) * H_LD + koff;
    const unsigned short* pA1 = hbuf + (size_t)(1 * 16 + l15) * H_LD + koff;
    const unsigned short* pA2 = hbuf + (size_t)(2 * 16 + l15) * H_LD + koff;
    const size_t kstr = (size_t)56 * 512;
    const unsigned short* pB = w3p + (((size_t)(w * 7)) * 64 + lane) * 8;
    short8 bA[7], bB[7];
    #pragma unroll
    for (int nb = 0; nb < 7; ++nb) bA[nb] = *(const short8*)(pB + nb * 512);
    pB += kstr;
    #pragma unroll 1
    for (int kb = 0; kb < 48; kb += 2) {
      #pragma unroll
      for (int nb = 0; nb < 7; ++nb) bB[nb] = *(const short8*)(pB + nb * 512);
      pB += kstr;
      {
        short8 a0 = *(const short8*)(pA0 + kb * 32);
        short8 a1 = *(const short8*)(pA1 + kb * 32);
        short8 a2 = *(const short8*)(pA2 + kb * 32);
        __builtin_amdgcn_s_setprio(1);
        #pragma unroll
        for (int nb = 0; nb < 7; ++nb) {
          acc3[0][nb] = MFMA_BF16(a0, bA[nb], acc3[0][nb]);
          acc3[1][nb] = MFMA_BF16(a1, bA[nb], acc3[1][nb]);
          acc3[2][nb] = MFMA_BF16(a2, bA[nb], acc3[2][nb]);
        }
        __builtin_amdgcn_s_setprio(0);
      }
      if (kb + 2 < 48) {
        #pragma unroll
        for (int nb = 0; nb < 7; ++nb) bA[nb] = *(const short8*)(pB + nb * 512);
      }
      pB += kstr;
      {
        short8 a0 = *(const short8*)(pA0 + kb * 32 + 32);
        short8 a1 = *(const short8*)(pA1 + kb * 32 + 32);
        short8 a2 = *(const short8*)(pA2 + kb * 32 + 32);
        __builtin_amdgcn_s_setprio(1);
        #pragma unroll
        for (int nb = 0; nb < 7; ++nb) {
          acc3[0][nb] = MFMA_BF16(a0, bB[nb], acc3[0][nb]);
          acc3[1][nb] = MFMA_BF16(a1, bB[nb], acc3[1][nb]);
          acc3[2][nb] = MFMA_BF16(a2, bB[nb], acc3[2][nb]);
        }
        __builtin_amdgcn_s_setprio(0);
      }
    }
  }
  __syncthreads();   // all hbuf A-reads done; scratch may now alias hbuf

  // ================= spline: wave w owns dims 8w..8w+7, all rows =============
  // per-wave f32 scratch [16][SW_LD] aliased into hbuf region
  float* sw = (float*)smem + (size_t)w * (16 * SW_LD);

  #pragma unroll 1
  for (int rb = 0; rb < RB; ++rb) {
    // write this 16-row chunk of GEMM3 output (+bias) into scratch
    {
      float* wp = sw + (size_t)(l4 * 4) * SW_LD + l15;
      #pragma unroll
      for (int nb = 0; nb < 7; ++nb) {
        const float bb = b3[w * 112 + nb * 16 + l15];
        #pragma unroll
        for (int i = 0; i < 4; ++i)
          wp[(size_t)i * SW_LD + nb * 16] = acc3[rb][nb][i] + bb;
      }
    }
    __syncthreads();
    // lane -> (row' = l15, dims d' = l4 and l4+4)
    const int grow = b0 + rb * 16 + l15;
    const bool valid = grow < BATCH;
    const int gr = valid ? grow : BATCH - 1;
    const int d1i = l4, d2i = l4 + 4;
    float z1, lad1, z2, lad2;
    const float xv1 = x[(size_t)gr * DIMX + w * 8 + d1i];
    const float xv2 = x[(size_t)gr * DIMX + w * 8 + d2i];
    spline_eval(&sw[l15 * SW_LD + d1i * 14], xv1, z1, lad1);
    spline_eval(&sw[l15 * SW_LD + d2i * 14], xv2, z2, lad2);
    if (valid) {
      zout[(size_t)grow * DIMX + w * 8 + d1i] = z1;
      zout[(size_t)grow * DIMX + w * 8 + d2i] = z2;
    }
    float ls = lad1 + lad2;
    ls += __shfl_xor(ls, 16, 64);
    ls += __shfl_xor(ls, 32, 64);
    if (lane < 16) red[w * 48 + rb * 16 + l15] = ls;   // wave's 8-dim row partial
    __syncthreads();
  }

  if (t < BM && b0 + t < BATCH) {
    float s = 0.f;
    #pragma unroll
    for (int w8 = 0; w8 < 8; ++w8) s += red[w8 * 48 + t];
    ladout[b0 + t] = s;
  }
}

// ---------------------------------------------------------------------------
extern "C" void kernel_launch(void* const* d_in, const int* in_sizes, int n_in,
                              void* d_out, int out_size, void* d_ws, size_t ws_size,
                              hipStream_t stream) {
  const float* x   = (const float*)d_in[0];
  const float* feat= (const float*)d_in[1];
  const float* w1  = (const float*)d_in[2];   // [1536][192]  pre-masked
  const float* b1  = (const float*)d_in[3];
  const float* g1  = (const float*)d_in[4];
  const float* be1 = (const float*)d_in[5];
  const float* w2  = (const float*)d_in[6];   // [1536][1536] pre-masked
  const float* b2  = (const float*)d_in[7];
  const float* g2  = (const float*)d_in[8];
  const float* be2 = (const float*)d_in[9];
  const float* w3  = (const float*)d_in[10];  // [896][1536]  pre-masked
  const float* b3  = (const float*)d_in[11];
  // masks unused: weights arrive pre-masked (mask is 0/1, idempotent).

  unsigned short* w1p = (unsigned short*)d_ws;                 // 576 tiles
  unsigned short* w2p = w1p + (size_t)576 * 512;               // 4608 tiles
  unsigned short* w3p = w2p + (size_t)4608 * 512;              // 2688 tiles

  pack_w<<<144,  256, 0, stream>>>(w1, w1p, WIDTH, IN1);
  pack_w<<<1152, 256, 0, stream>>>(w2, w2p, WIDTH, WIDTH);
  pack_w<<<672,  256, 0, stream>>>(w3, w3p, ONC, WIDTH);

  float* zout   = (float*)d_out;
  float* ladout = zout + (size_t)BATCH * DIMX;
  nsf_fused<<<NBLK, NT, 0, stream>>>(x, feat, w1p, b1, g1, be1,
                                     w2p, b2, g2, be2, w3p, b3,
                                     zout, ladout);
}

// Round 5
// 376.107 us; speedup vs baseline: 1.0887x; 1.0545x over previous
//
#include <hip/hip_runtime.h>
#include <math.h>

// Problem constants
#define BATCH   32768
#define DIMX    64
#define FEATD   128
#define IN1     192      // FEATDIM + DIM
#define WIDTH   1536
#define ONC     896      // DIM * (3K-1)

// Tiling
#define NT      512      // 8 waves
#define H_LD    1544     // h row stride in bf16 elems (1536 + 8 pad)
#define IN_LD   200      // input row stride in bf16 elems (192 + 8 pad)
#define SW_LD   114      // spline scratch row stride in f32 (112 + 2 pad)

typedef __attribute__((ext_vector_type(8))) short short8;
typedef __attribute__((ext_vector_type(4))) float f32x4;

#define MFMA_BF16(a,b,c) __builtin_amdgcn_mfma_f32_16x16x32_bf16((a),(b),(c),0,0,0)

__device__ __forceinline__ unsigned short f2bf(float f) {
  unsigned u = __builtin_bit_cast(unsigned, f);
  u += 0x7fffu + ((u >> 16) & 1u);            // round-to-nearest-even
  return (unsigned short)(u >> 16);
}
__device__ __forceinline__ float softplusf(float t) {
  return fmaxf(t, 0.f) + log1pf(expf(-fabsf(t)));
}

// ---------------------------------------------------------------------------
// Pack weight W [N][K] f32 (pre-masked) into MFMA B-fragment tiles, bf16:
//   out[(kb*(N/16)+nb)*512 + lane*8 + j] = bf16( W[nb*16+(lane&15)][kb*32+(lane>>4)*8+j] )
// ---------------------------------------------------------------------------
__global__ __launch_bounds__(256) void pack_w(const float* __restrict__ W,
                                              unsigned short* __restrict__ out,
                                              int N, int K) {
  const int wv = (blockIdx.x * 256 + threadIdx.x) >> 6;   // tile id
  const int lane = threadIdx.x & 63;
  const int ntiles = (K / 32) * (N / 16);
  if (wv >= ntiles) return;
  const int nbt = N / 16;
  const int kb = wv / nbt, nb = wv - kb * nbt;
  const int n = nb * 16 + (lane & 15);
  const int k = kb * 32 + (lane >> 4) * 8;
  const float* src = W + (size_t)n * K + k;
  const float4 v0 = *(const float4*)src;
  const float4 v1 = *(const float4*)(src + 4);
  short8 o;
  o[0] = (short)f2bf(v0.x); o[1] = (short)f2bf(v0.y);
  o[2] = (short)f2bf(v0.z); o[3] = (short)f2bf(v0.w);
  o[4] = (short)f2bf(v1.x); o[5] = (short)f2bf(v1.y);
  o[6] = (short)f2bf(v1.z); o[7] = (short)f2bf(v1.w);
  *(short8*)(out + ((size_t)wv * 64 + lane) * 8) = o;
}

// ---------------------------------------------------------------------------
// Pipelined B-stream GEMM: NKB k-blocks, NTILE n-tiles per wave slice,
// 3-deep B register buffering (distance ~2-3 MFMA phases -> covers L3 latency),
// A fragments double-buffered 2 phases ahead. acc[rb*ASTR + nb].
// ---------------------------------------------------------------------------
template<int RBT, int NTILE, int ASTR, int NKB>
__device__ __forceinline__ void gemm_stream(
    const unsigned short* __restrict__ pB, size_t kstr,
    const unsigned short* hbase, int ald,
    f32x4* acc, int l15, int l4)
{
  const unsigned short* pA[RBT];
  #pragma unroll
  for (int rb = 0; rb < RBT; ++rb) pA[rb] = hbase + (size_t)(rb * 16 + l15) * ald + l4 * 8;

  short8 b0[NTILE], b1[NTILE], b2[NTILE];
  #pragma unroll
  for (int nb = 0; nb < NTILE; ++nb) b0[nb] = *(const short8*)(pB + nb * 512);
  pB += kstr;
  #pragma unroll
  for (int nb = 0; nb < NTILE; ++nb) b1[nb] = *(const short8*)(pB + nb * 512);
  pB += kstr;
  #pragma unroll
  for (int nb = 0; nb < NTILE; ++nb) b2[nb] = *(const short8*)(pB + nb * 512);
  pB += kstr;

  short8 aX[RBT], aY[RBT], aZ[RBT];
  #pragma unroll
  for (int rb = 0; rb < RBT; ++rb) aX[rb] = *(const short8*)(pA[rb]);
  #pragma unroll
  for (int rb = 0; rb < RBT; ++rb) aY[rb] = *(const short8*)(pA[rb] + 32);

  #pragma unroll 1
  for (int it = 0; it < NKB / 3 - 1; ++it) {
    const int kb = it * 3;
    // phase 0: consume (aX, b0)=kb; prefetch aZ=A(kb+2), b0<-kb+3
    #pragma unroll
    for (int rb = 0; rb < RBT; ++rb) aZ[rb] = *(const short8*)(pA[rb] + (kb + 2) * 32);
    __builtin_amdgcn_s_setprio(1);
    #pragma unroll
    for (int nb = 0; nb < NTILE; ++nb)
      #pragma unroll
      for (int rb = 0; rb < RBT; ++rb)
        acc[rb * ASTR + nb] = MFMA_BF16(aX[rb], b0[nb], acc[rb * ASTR + nb]);
    __builtin_amdgcn_s_setprio(0);
    #pragma unroll
    for (int nb = 0; nb < NTILE; ++nb) b0[nb] = *(const short8*)(pB + nb * 512);
    pB += kstr;
    // phase 1: consume (aY, b1)=kb+1; prefetch aX=A(kb+3), b1<-kb+4
    #pragma unroll
    for (int rb = 0; rb < RBT; ++rb) aX[rb] = *(const short8*)(pA[rb] + (kb + 3) * 32);
    __builtin_amdgcn_s_setprio(1);
    #pragma unroll
    for (int nb = 0; nb < NTILE; ++nb)
      #pragma unroll
      for (int rb = 0; rb < RBT; ++rb)
        acc[rb * ASTR + nb] = MFMA_BF16(aY[rb], b1[nb], acc[rb * ASTR + nb]);
    __builtin_amdgcn_s_setprio(0);
    #pragma unroll
    for (int nb = 0; nb < NTILE; ++nb) b1[nb] = *(const short8*)(pB + nb * 512);
    pB += kstr;
    // phase 2: consume (aZ, b2)=kb+2; prefetch aY=A(kb+4), b2<-kb+5
    #pragma unroll
    for (int rb = 0; rb < RBT; ++rb) aY[rb] = *(const short8*)(pA[rb] + (kb + 4) * 32);
    __builtin_amdgcn_s_setprio(1);
    #pragma unroll
    for (int nb = 0; nb < NTILE; ++nb)
      #pragma unroll
      for (int rb = 0; rb < RBT; ++rb)
        acc[rb * ASTR + nb] = MFMA_BF16(aZ[rb], b2[nb], acc[rb * ASTR + nb]);
    __builtin_amdgcn_s_setprio(0);
    #pragma unroll
    for (int nb = 0; nb < NTILE; ++nb) b2[nb] = *(const short8*)(pB + nb * 512);
    pB += kstr;
  }
  // epilogue: kb = NKB-3
  {
    const int kb = NKB - 3;
    #pragma unroll
    for (int rb = 0; rb < RBT; ++rb) aZ[rb] = *(const short8*)(pA[rb] + (kb + 2) * 32);
    __builtin_amdgcn_s_setprio(1);
    #pragma unroll
    for (int nb = 0; nb < NTILE; ++nb)
      #pragma unroll
      for (int rb = 0; rb < RBT; ++rb)
        acc[rb * ASTR + nb] = MFMA_BF16(aX[rb], b0[nb], acc[rb * ASTR + nb]);
    #pragma unroll
    for (int nb = 0; nb < NTILE; ++nb)
      #pragma unroll
      for (int rb = 0; rb < RBT; ++rb)
        acc[rb * ASTR + nb] = MFMA_BF16(aY[rb], b1[nb], acc[rb * ASTR + nb]);
    #pragma unroll
    for (int nb = 0; nb < NTILE; ++nb)
      #pragma unroll
      for (int rb = 0; rb < RBT; ++rb)
        acc[rb * ASTR + nb] = MFMA_BF16(aZ[rb], b2[nb], acc[rb * ASTR + nb]);
    __builtin_amdgcn_s_setprio(0);
  }
}

// ---------------------------------------------------------------------------
// bias + leaky + LayerNorm on MFMA C fragments (12 n-tiles/wave, RBT row-blocks)
// ---------------------------------------------------------------------------
template<int RBT>
__device__ __forceinline__ void act_ln(f32x4 (&acc)[RBT][12],
    const float* __restrict__ bias, const float* __restrict__ gam,
    const float* __restrict__ bet, int colbase,
    unsigned short* hbuf, float* red, float* mstd,
    int t, int w, int l15, int l4)
{
  #pragma unroll
  for (int nb = 0; nb < 12; ++nb) {
    const float bb = bias[colbase + nb * 16 + l15];
    #pragma unroll
    for (int rb = 0; rb < RBT; ++rb)
      #pragma unroll
      for (int i = 0; i < 4; ++i) {
        float v = acc[rb][nb][i] + bb;
        acc[rb][nb][i] = v > 0.f ? v : 0.2f * v;
      }
  }
  #pragma unroll
  for (int rb = 0; rb < RBT; ++rb)
    #pragma unroll
    for (int i = 0; i < 4; ++i) {
      float ss = 0.f, qq = 0.f;
      #pragma unroll
      for (int nb = 0; nb < 12; ++nb) {
        const float v = acc[rb][nb][i];
        ss += v; qq += v * v;
      }
      #pragma unroll
      for (int o = 1; o < 16; o <<= 1) { ss += __shfl_xor(ss, o, 64); qq += __shfl_xor(qq, o, 64); }
      if (l15 == 0) {
        const int r = rb * 16 + l4 * 4 + i;
        red[w * 96 + r] = ss;
        red[w * 96 + 48 + r] = qq;
      }
    }
  __syncthreads();
  if (t < 16 * RBT) {
    float ss = 0.f, qq = 0.f;
    #pragma unroll
    for (int w8 = 0; w8 < 8; ++w8) { ss += red[w8 * 96 + t]; qq += red[w8 * 96 + 48 + t]; }
    const float m = ss * (1.f / (float)WIDTH);
    const float v = qq * (1.f / (float)WIDTH) - m * m;
    mstd[t] = m;
    mstd[48 + t] = rsqrtf(fmaxf(v, 0.f) + 1e-5f);
  }
  __syncthreads();
  float mm[RBT][4], rr[RBT][4];
  #pragma unroll
  for (int rb = 0; rb < RBT; ++rb)
    #pragma unroll
    for (int i = 0; i < 4; ++i) {
      const int r = rb * 16 + l4 * 4 + i;
      mm[rb][i] = mstd[r]; rr[rb][i] = mstd[48 + r];
    }
  #pragma unroll
  for (int rb = 0; rb < RBT; ++rb) {
    unsigned short* wp = hbuf + (size_t)(rb * 16 + l4 * 4) * H_LD + colbase + l15;
    #pragma unroll
    for (int nb = 0; nb < 12; ++nb) {
      const int col = colbase + nb * 16 + l15;
      const float gg = gam[col], ee = bet[col];
      #pragma unroll
      for (int i = 0; i < 4; ++i)
        wp[(size_t)i * H_LD + nb * 16] =
            f2bf((acc[rb][nb][i] - mm[rb][i]) * rr[rb][i] * gg + ee);
    }
  }
  __syncthreads();
}

// ---------------------------------------------------------------------------
// RQS spline for one (row, dim): o = 14 params [W0..4, H0..4, D0..3]
// ---------------------------------------------------------------------------
__device__ __forceinline__ void spline_eval(const float* __restrict__ o, float xv,
                                            float& zret, float& ladd) {
  const float Wv0 = o[0], Wv1 = o[1], Wv2 = o[2], Wv3 = o[3], Wv4 = o[4];
  const float Hv0 = o[5], Hv1 = o[6], Hv2 = o[7], Hv3 = o[8], Hv4 = o[9];
  const float Dv0 = o[10], Dv1 = o[11], Dv2 = o[12], Dv3 = o[13];

  float mw = fmaxf(fmaxf(fmaxf(Wv0, Wv1), fmaxf(Wv2, Wv3)), Wv4);
  float e0 = expf(Wv0 - mw), e1 = expf(Wv1 - mw), e2 = expf(Wv2 - mw),
        e3 = expf(Wv3 - mw), e4 = expf(Wv4 - mw);
  float inv = 0.995f / (e0 + e1 + e2 + e3 + e4);
  const float wd0 = 0.001f + e0 * inv, wd1 = 0.001f + e1 * inv,
              wd2 = 0.001f + e2 * inv, wd3 = 0.001f + e3 * inv;
  const float c1 = wd0, c2 = c1 + wd1, c3 = c2 + wd2, c4 = c3 + wd3;
  const float wi0 = c1, wi1 = c2 - c1, wi2 = c3 - c2, wi3 = c4 - c3, wi4 = 1.f - c4;

  float mh = fmaxf(fmaxf(fmaxf(Hv0, Hv1), fmaxf(Hv2, Hv3)), Hv4);
  float f0 = expf(Hv0 - mh), f1e = expf(Hv1 - mh), f2e = expf(Hv2 - mh),
        f3e = expf(Hv3 - mh), f4e = expf(Hv4 - mh);
  float invh = 0.995f / (f0 + f1e + f2e + f3e + f4e);
  const float hd0 = 0.001f + f0 * invh, hd1 = 0.001f + f1e * invh,
              hd2 = 0.001f + f2e * invh, hd3 = 0.001f + f3e * invh;
  const float g1c = hd0, g2c = g1c + hd1, g3c = g2c + hd2, g4c = g3c + hd3;
  const float hi0 = g1c, hi1 = g2c - g1c, hi2 = g3c - g2c, hi3 = g4c - g3c, hi4 = 1.f - g4c;

  const float dv1 = 0.001f + softplusf(Dv0), dv2 = 0.001f + softplusf(Dv1),
              dv3 = 0.001f + softplusf(Dv2), dv4 = 0.001f + softplusf(Dv3);

  const float s = 1.f / (1.f + expf(-xv));
  const int idx = (int)(s >= c1) + (int)(s >= c2) + (int)(s >= c3) + (int)(s >= c4);

  const float in_cw = idx == 0 ? 0.f : idx == 1 ? c1  : idx == 2 ? c2  : idx == 3 ? c3  : c4;
  const float in_w  = idx == 0 ? wi0 : idx == 1 ? wi1 : idx == 2 ? wi2 : idx == 3 ? wi3 : wi4;
  const float in_h  = idx == 0 ? hi0 : idx == 1 ? hi1 : idx == 2 ? hi2 : idx == 3 ? hi3 : hi4;
  const float in_ch = idx == 0 ? 0.f : idx == 1 ? g1c : idx == 2 ? g2c : idx == 3 ? g3c : g4c;
  const float d0    = idx == 0 ? 1.f : idx == 1 ? dv1 : idx == 2 ? dv2 : idx == 3 ? dv3 : dv4;
  const float d1    = idx == 0 ? dv1 : idx == 1 ? dv2 : idx == 2 ? dv3 : idx == 3 ? dv4 : 1.f;

  const float delta = in_h / in_w;
  const float th  = (s - in_cw) / in_w;
  const float omt = 1.f - th;
  const float t1  = th * omt;
  const float num = in_h * (delta * th * th + d0 * t1);
  const float den = delta + (d0 + d1 - 2.f * delta) * t1;
  float outv = in_ch + num / den;
  const float dnum = delta * delta * (d1 * th * th + 2.f * delta * t1 + d0 * omt * omt);
  const float lad_rqs = logf(dnum) - 2.f * logf(den);
  outv = outv * 0.999998f + 1e-6f;
  const float lo = logf(outv), l1m = logf(1.f - outv);
  const float logds = -softplusf(-xv) - softplusf(xv);
  zret = lo - l1m;
  ladd = logds + lad_rqs - lo - l1m;
}

// ---------------------------------------------------------------------------
// Fused kernel (RBT 16-row blocks per workgroup; rowbase = first batch row)
// ---------------------------------------------------------------------------
template<int RBT>
__global__ __launch_bounds__(NT, 2) void nsf_fused(
    const float* __restrict__ x, const float* __restrict__ feat,
    const unsigned short* __restrict__ w1p, const float* __restrict__ b1,
    const float* __restrict__ g1, const float* __restrict__ be1,
    const unsigned short* __restrict__ w2p, const float* __restrict__ b2,
    const float* __restrict__ g2, const float* __restrict__ be2,
    const unsigned short* __restrict__ w3p, const float* __restrict__ b3,
    float* __restrict__ zout, float* __restrict__ ladout, int rowbase)
{
  constexpr int BMT = 16 * RBT;
  __shared__ __align__(16) unsigned char smem[BMT * H_LD * 2 + 768 * 4 + 96 * 4];
  unsigned short* hbuf = (unsigned short*)smem;
  float* red  = (float*)(smem + BMT * H_LD * 2);
  float* mstd = red + 768;

  const int t = threadIdx.x;
  const int lane = t & 63, w = t >> 6;
  const int l15 = lane & 15, l4 = lane >> 4;
  const int b0 = rowbase + blockIdx.x * BMT;

  // ---- stage concat([feat, x]) as bf16 ----
  for (int idx = t; idx < BMT * IN1; idx += NT) {
    const int r = idx / IN1, c = idx - r * IN1;
    const int row = b0 + r;
    const float v = (c < FEATD) ? feat[(size_t)row * FEATD + c]
                                : x[(size_t)row * DIMX + (c - FEATD)];
    hbuf[r * IN_LD + c] = f2bf(v);
  }
  __syncthreads();

  // ================= GEMM1: K=192 (6 kblks), 2 groups of 6 tiles =============
  f32x4 acc[RBT][12];
  #pragma unroll
  for (int rb = 0; rb < RBT; ++rb)
    #pragma unroll
    for (int nb = 0; nb < 12; ++nb) acc[rb][nb] = (f32x4){0.f, 0.f, 0.f, 0.f};

  #pragma unroll
  for (int g = 0; g < 2; ++g)
    gemm_stream<RBT, 6, 12, 6>(
        w1p + (((size_t)(w * 12 + g * 6)) * 64 + lane) * 8, (size_t)96 * 512,
        hbuf, IN_LD, &acc[0][g * 6], l15, l4);
  act_ln<RBT>(acc, b1, g1, be1, w * 192, hbuf, red, mstd, t, w, l15, l4);

  // ================= GEMM2: K=1536 (48 kblks), 2 groups of 6 tiles ===========
  #pragma unroll
  for (int rb = 0; rb < RBT; ++rb)
    #pragma unroll
    for (int nb = 0; nb < 12; ++nb) acc[rb][nb] = (f32x4){0.f, 0.f, 0.f, 0.f};

  #pragma unroll
  for (int g = 0; g < 2; ++g)
    gemm_stream<RBT, 6, 12, 48>(
        w2p + (((size_t)(w * 12 + g * 6)) * 64 + lane) * 8, (size_t)96 * 512,
        hbuf, H_LD, &acc[0][g * 6], l15, l4);
  act_ln<RBT>(acc, b2, g2, be2, w * 192, hbuf, red, mstd, t, w, l15, l4);

  // ================= GEMM3: N=896, wave cols w*112..+112 (7 tiles) ===========
  f32x4 acc3[RBT][7];
  #pragma unroll
  for (int rb = 0; rb < RBT; ++rb)
    #pragma unroll
    for (int nb = 0; nb < 7; ++nb) acc3[rb][nb] = (f32x4){0.f, 0.f, 0.f, 0.f};

  gemm_stream<RBT, 7, 7, 48>(
      w3p + (((size_t)(w * 7)) * 64 + lane) * 8, (size_t)56 * 512,
      hbuf, H_LD, &acc3[0][0], l15, l4);
  __syncthreads();   // all hbuf A-reads done; scratch may now alias hbuf

  // ================= spline: wave w owns dims 8w..8w+7, all rows =============
  float* sw = (float*)smem + (size_t)w * (16 * SW_LD);

  #pragma unroll 1
  for (int rb = 0; rb < RBT; ++rb) {
    {
      float* wp = sw + (size_t)(l4 * 4) * SW_LD + l15;
      #pragma unroll
      for (int nb = 0; nb < 7; ++nb) {
        const float bb = b3[w * 112 + nb * 16 + l15];
        #pragma unroll
        for (int i = 0; i < 4; ++i)
          wp[(size_t)i * SW_LD + nb * 16] = acc3[rb][nb][i] + bb;
      }
    }
    __syncthreads();
    const int grow = b0 + rb * 16 + l15;
    const int d1i = l4, d2i = l4 + 4;
    float z1, lad1, z2, lad2;
    const float xv1 = x[(size_t)grow * DIMX + w * 8 + d1i];
    const float xv2 = x[(size_t)grow * DIMX + w * 8 + d2i];
    spline_eval(&sw[l15 * SW_LD + d1i * 14], xv1, z1, lad1);
    spline_eval(&sw[l15 * SW_LD + d2i * 14], xv2, z2, lad2);
    zout[(size_t)grow * DIMX + w * 8 + d1i] = z1;
    zout[(size_t)grow * DIMX + w * 8 + d2i] = z2;
    float ls = lad1 + lad2;
    ls += __shfl_xor(ls, 16, 64);
    ls += __shfl_xor(ls, 32, 64);
    if (lane < 16) red[w * 48 + rb * 16 + l15] = ls;
    __syncthreads();
  }

  if (t < BMT) {
    float s = 0.f;
    #pragma unroll
    for (int w8 = 0; w8 < 8; ++w8) s += red[w8 * 48 + t];
    ladout[b0 + t] = s;
  }
}

// ---------------------------------------------------------------------------
extern "C" void kernel_launch(void* const* d_in, const int* in_sizes, int n_in,
                              void* d_out, int out_size, void* d_ws, size_t ws_size,
                              hipStream_t stream) {
  const float* x   = (const float*)d_in[0];
  const float* feat= (const float*)d_in[1];
  const float* w1  = (const float*)d_in[2];   // [1536][192]  pre-masked
  const float* b1  = (const float*)d_in[3];
  const float* g1  = (const float*)d_in[4];
  const float* be1 = (const float*)d_in[5];
  const float* w2  = (const float*)d_in[6];   // [1536][1536] pre-masked
  const float* b2  = (const float*)d_in[7];
  const float* g2  = (const float*)d_in[8];
  const float* be2 = (const float*)d_in[9];
  const float* w3  = (const float*)d_in[10];  // [896][1536]  pre-masked
  const float* b3  = (const float*)d_in[11];
  // masks unused: weights arrive pre-masked (mask is 0/1, idempotent).

  unsigned short* w1p = (unsigned short*)d_ws;                 // 576 tiles
  unsigned short* w2p = w1p + (size_t)576 * 512;               // 4608 tiles
  unsigned short* w3p = w2p + (size_t)4608 * 512;              // 2688 tiles

  pack_w<<<144,  256, 0, stream>>>(w1, w1p, WIDTH, IN1);
  pack_w<<<1152, 256, 0, stream>>>(w2, w2p, WIDTH, WIDTH);
  pack_w<<<672,  256, 0, stream>>>(w3, w3p, ONC, WIDTH);

  float* zout   = (float*)d_out;
  float* ladout = zout + (size_t)BATCH * DIMX;
  // Exact-fill mixed grid: 512 x 48 rows + 256 x 32 rows = 32768 rows,
  // every scheduling round fully occupies the 256 CUs.
  nsf_fused<3><<<512, NT, 0, stream>>>(x, feat, w1p, b1, g1, be1,
                                       w2p, b2, g2, be2, w3p, b3,
                                       zout, ladout, 0);
  nsf_fused<2><<<256, NT, 0, stream>>>(x, feat, w1p, b1, g1, be1,
                                       w2p, b2, g2, be2, w3p, b3,
                                       zout, ladout, 24576);
}